// Round 6
// baseline (1338.711 us; speedup 1.0000x reference)
//
#include <hip/hip_runtime.h>
#include <math.h>

#define BB 64
#define TT 1024
#define DD 32
#define GG 128   // 4*D
#define VOCABN 10000
#define QLEN 100
#define N_LIST_BYTES (65536 * 4)

__device__ __forceinline__ float fsig(float x) {
    return __builtin_amdgcn_rcpf(1.0f + __expf(-x));
}
__device__ __forceinline__ float readlane_f(float v, int l) {
    return __int_as_float(__builtin_amdgcn_readlane(__float_as_int(v), l));
}

// ---------------------------------------------------------------------------
// Kernel 1: xg[b,t,j] = b_lstm[j] + sum_d emb[id[b,t],d] * k_lstm[d,j]
// 4 tokens per barrier pair.
// ---------------------------------------------------------------------------
__global__ __launch_bounds__(128) void k_xg(const int* __restrict__ ids,
                                            const float* __restrict__ emb,
                                            const float* __restrict__ klstm,
                                            const float* __restrict__ bias,
                                            float* __restrict__ xg) {
    const int j = threadIdx.x;  // 0..127
    float kc[DD];
#pragma unroll
    for (int d = 0; d < DD; ++d) kc[d] = klstm[d * GG + j];
    const float bj = bias[j];
    __shared__ float e4[4][DD];
    const int PPB = (BB * TT) / gridDim.x;  // 128 tokens per block
    const int p0 = blockIdx.x * PPB;
    for (int p = p0; p < p0 + PPB; p += 4) {
        {
            int tok = p + (j >> 5);
            int id = ids[tok];
            if ((unsigned)id >= VOCABN) id = 0;
            e4[j >> 5][j & 31] = emb[id * DD + (j & 31)];
        }
        __syncthreads();
#pragma unroll
        for (int i = 0; i < 4; ++i) {
            float z = bj;
#pragma unroll
            for (int d = 0; d < DD; ++d) z += e4[i][d] * kc[d];
            xg[(size_t)(p + i) * GG + j] = z;
        }
        __syncthreads();
    }
}

// ---------------------------------------------------------------------------
// Kernel 2: LSTM scan — 4 INDEPENDENT BATCH CHAINS PER WAVE (ILP).
// R4 measurement: single-chain wave stalls ~75% of cycles on its serial
// dependency chain (VALUBusy 17.6% on active CUs); VGPR fix (60->132) was
// neutral, clock-probe was neutral. So fill the stall slots with 3 more
// independent chains: 4 batches/wave, same step body per batch (proven
// correct since R1). Weights rka/rkb shared across batches. Grid 16x64.
// ---------------------------------------------------------------------------
#define BPW 4
#define UU 4
__global__
__attribute__((amdgpu_flat_work_group_size(64, 64)))
__attribute__((amdgpu_waves_per_eu(1, 1)))
void k_lstm_scan(const float* __restrict__ xg,
                 const float* __restrict__ rk,
                 float* __restrict__ hout) {
    const int wb = blockIdx.x * BPW;
    const int l = threadIdx.x;       // 0..63
    const int d = l & 31;
    const bool hi = l >= 32;
    const int ga = (hi ? 32 : 0) + d;   // i (lo) / f (hi)
    const int gb = (hi ? 96 : 64) + d;  // g (lo) / o (hi)
    float rka[DD], rkb[DD];
#pragma unroll
    for (int k = 0; k < DD; ++k) { rka[k] = rk[k * GG + ga]; rkb[k] = rk[k * GG + gb]; }

    float h[BPW], c[BPW];
#pragma unroll
    for (int i = 0; i < BPW; ++i) { h[i] = 0.0f; c[i] = 0.0f; }

    float pa[BPW][UU], pb[BPW][UU];
#pragma unroll
    for (int i = 0; i < BPW; ++i) {
        const float* xgb = xg + (size_t)(wb + i) * TT * GG;
#pragma unroll
        for (int u = 0; u < UU; ++u) {
            pa[i][u] = xgb[u * GG + ga];
            pb[i][u] = xgb[u * GG + gb];
        }
    }

    for (int t0 = 0; t0 < TT; t0 += UU) {
        float na[BPW][UU], nb[BPW][UU];
        const int tn0 = (t0 + UU < TT) ? (t0 + UU) : t0;
#pragma unroll
        for (int i = 0; i < BPW; ++i) {
            const float* xgb = xg + (size_t)(wb + i) * TT * GG;
#pragma unroll
            for (int u = 0; u < UU; ++u) {
                na[i][u] = xgb[(tn0 + u) * GG + ga];
                nb[i][u] = xgb[(tn0 + u) * GG + gb];
            }
        }
#pragma unroll
        for (int u = 0; u < UU; ++u) {
            float za[BPW], zb[BPW];
#pragma unroll
            for (int i = 0; i < BPW; ++i) { za[i] = pa[i][u]; zb[i] = pb[i][u]; }
            // 4 batches interleaved: 8 independent FMA chains fill stalls
#pragma unroll
            for (int k = 0; k < DD; k += 2) {
#pragma unroll
                for (int i = 0; i < BPW; ++i) {
                    float h0 = readlane_f(h[i], k);
                    float h1 = readlane_f(h[i], k + 1);
                    za[i] = fmaf(h0, rka[k], za[i]);
                    zb[i] = fmaf(h0, rkb[k], zb[i]);
                    za[i] = fmaf(h1, rka[k + 1], za[i]);
                    zb[i] = fmaf(h1, rkb[k + 1], zb[i]);
                }
            }
#pragma unroll
            for (int i = 0; i < BPW; ++i) {
                float a = fsig(za[i]);                      // sig(i) lo / sig(f) hi
                float zbm = hi ? zb[i] : 2.0f * zb[i];
                float s2 = fsig(zbm);
                float bv = hi ? s2 : 2.0f * s2 - 1.0f;      // sig(o) hi / tanh(g) lo
                float fg = __shfl_xor(a, 32);               // lo lanes get sig(f)
                float og = __shfl_xor(bv, 32);              // lo lanes get sig(o)
                c[i] = fmaf(fg, c[i], a * bv);
                float tc = 2.0f * fsig(2.0f * c[i]) - 1.0f; // tanh(c)
                h[i] = og * tc;
            }
            if (!hi) {
#pragma unroll
                for (int i = 0; i < BPW; ++i)
                    hout[((size_t)(wb + i) * TT + (t0 + u)) * DD + d] = h[i];
            }
        }
#pragma unroll
        for (int i = 0; i < BPW; ++i)
#pragma unroll
            for (int u = 0; u < UU; ++u) { pa[i][u] = na[i][u]; pb[i][u] = nb[i][u]; }
    }
}

// ---------------------------------------------------------------------------
// Kernel 3: attention — REVERTED to the proven R1 version (LDS key tiles).
// R4's scalar-load rewrite regressed ~+116 µs; this one passed at 650 total.
// Split-K flash without max-subtraction (|score|<32, exp can't overflow).
// ---------------------------------------------------------------------------
__global__ __launch_bounds__(256, 4) void k_attn(const float* __restrict__ h,
                                                 float* __restrict__ ctx) {
    __shared__ float smem[4 * 64 * DD];  // 32 KB: 4 wave-private key tiles
    const int tid = threadIdx.x;
    const int w = tid >> 6;     // split / wave id
    const int lane = tid & 63;  // q row within tile
    const int b = blockIdx.x >> 4;
    const int qt = blockIdx.x & 15;
    const float* hb = h + (size_t)b * TT * DD;
    const int q = qt * 64 + lane;

    float qq[DD], aa[DD];
    {
        const float4* qsrc = (const float4*)(hb + (size_t)q * DD);
#pragma unroll
        for (int n = 0; n < 8; ++n) {
            float4 v = qsrc[n];
            qq[4 * n] = v.x; qq[4 * n + 1] = v.y; qq[4 * n + 2] = v.z; qq[4 * n + 3] = v.w;
        }
    }
#pragma unroll
    for (int n = 0; n < DD; ++n) aa[n] = 0.0f;
    float l = 0.0f;

    float* myk = smem + w * (64 * DD);
#pragma unroll 1
    for (int tile = 0; tile < 4; ++tile) {
        const float4* ksrc = (const float4*)(hb + (size_t)(w * 256 + tile * 64) * DD);
        float4* kd = (float4*)myk;
#pragma unroll
        for (int n = 0; n < 8; ++n) kd[lane + n * 64] = ksrc[lane + n * 64];
        // wave-private region: same-wave ds write->read ordering, no barrier
        for (int s = 0; s < 64; ++s) {
            const float4* kr = (const float4*)(myk + s * DD);
            float kk[DD];
#pragma unroll
            for (int n = 0; n < 8; ++n) {
                float4 v = kr[n];
                kk[4 * n] = v.x; kk[4 * n + 1] = v.y; kk[4 * n + 2] = v.z; kk[4 * n + 3] = v.w;
            }
            float t0 = 0.f, t1 = 0.f, t2 = 0.f, t3 = 0.f;
#pragma unroll
            for (int n = 0; n < DD; n += 4) {
                t0 = fmaf(kk[n], qq[n], t0);
                t1 = fmaf(kk[n + 1], qq[n + 1], t1);
                t2 = fmaf(kk[n + 2], qq[n + 2], t2);
                t3 = fmaf(kk[n + 3], qq[n + 3], t3);
            }
            float sc = (t0 + t1) + (t2 + t3);
            float e = __expf(sc);
            l += e;
#pragma unroll
            for (int n = 0; n < DD; ++n) aa[n] = fmaf(e, kk[n], aa[n]);
        }
    }

    // merge splits: sequential adds into macc[64][33] (reuses tile LDS)
    float* macc = smem;
    for (int ww = 0; ww < 4; ++ww) {
        __syncthreads();
        if (w == ww) {
            if (ww == 0) {
#pragma unroll
                for (int n = 0; n < DD; ++n) macc[lane * 33 + n] = aa[n];
                macc[lane * 33 + 32] = l;
            } else {
#pragma unroll
                for (int n = 0; n < DD; ++n) macc[lane * 33 + n] += aa[n];
                macc[lane * 33 + 32] += l;
            }
        }
    }
    __syncthreads();
    {
        const int r = tid >> 2;          // 0..63
        const int c0 = (tid & 3) * 8;    // 0,8,16,24
        float linv = __builtin_amdgcn_rcpf(macc[r * 33 + 32]);
        float o[8];
#pragma unroll
        for (int jj = 0; jj < 8; ++jj) o[jj] = macc[r * 33 + c0 + jj] * linv;
        float* crow = ctx + (size_t)b * TT * DD + (size_t)qt * 64 * DD;
        ((float4*)(crow + tid * 8))[0] = make_float4(o[0], o[1], o[2], o[3]);
        ((float4*)(crow + tid * 8))[1] = make_float4(o[4], o[5], o[6], o[7]);
    }
}

// ---------------------------------------------------------------------------
// Kernel 4: y[b,d,e] = sum_t ctx[b,t,d]*h[b,t,e];  yr = relu(y@W1+b1);
// out[b,d] = sigmoid(yr@W2+b2).  One block per batch, 256 threads.
// ---------------------------------------------------------------------------
__global__ __launch_bounds__(256) void k_ymlp(const float* __restrict__ ctx,
                                              const float* __restrict__ h,
                                              const float* __restrict__ W1,
                                              const float* __restrict__ b1,
                                              const float* __restrict__ W2,
                                              const float* __restrict__ b2,
                                              float* __restrict__ out) {
    const int b = blockIdx.x;
    const int tid = threadIdx.x;
    __shared__ __align__(16) float cs[128 * DD];
    __shared__ __align__(16) float hs[128 * DD];
    const float* cb = ctx + (size_t)b * TT * DD;
    const float* hb = h + (size_t)b * TT * DD;
    const int e = tid & 31;
    const int d0 = tid >> 5;
    float acc[4] = {0.f, 0.f, 0.f, 0.f};
    for (int kt = 0; kt < 8; ++kt) {
        const float4* s1 = (const float4*)(cb + (size_t)kt * 128 * DD);
        const float4* s2 = (const float4*)(hb + (size_t)kt * 128 * DD);
        float4* t1 = (float4*)cs;
        float4* t2 = (float4*)hs;
#pragma unroll
        for (int n = 0; n < 4; ++n) {
            t1[tid + n * 256] = s1[tid + n * 256];
            t2[tid + n * 256] = s2[tid + n * 256];
        }
        __syncthreads();
        for (int s = 0; s < 128; ++s) {
            float hv = hs[s * DD + e];
#pragma unroll
            for (int r = 0; r < 4; ++r) acc[r] += cs[s * DD + d0 + 8 * r] * hv;
        }
        __syncthreads();
    }
    __shared__ float ys[DD][DD];
#pragma unroll
    for (int r = 0; r < 4; ++r) ys[d0 + 8 * r][e] = acc[r];
    __syncthreads();
    __shared__ float yr[DD][33];
#pragma unroll
    for (int r = 0; r < 4; ++r) {
        float v = b1[e];
#pragma unroll
        for (int ee = 0; ee < DD; ++ee) v += ys[d0 + 8 * r][ee] * W1[ee * DD + e];
        yr[d0 + 8 * r][e] = fmaxf(v, 0.0f);
    }
    __syncthreads();
    if (tid < DD) {
        float v = b2[0];
#pragma unroll
        for (int ee = 0; ee < DD; ++ee) v += yr[tid][ee] * W2[ee];
        out[b * DD + tid] = 1.0f / (1.0f + expf(-v));
    }
}

// ---------------------------------------------------------------------------
// Kernel 5: zero-index queue. int4 loads + wave shfl-scan.
// ---------------------------------------------------------------------------
__global__ __launch_bounds__(256) void k_queue(const int* __restrict__ ids,
                                               int* __restrict__ list,
                                               float* __restrict__ outq) {
    const int tid = threadIdx.x;
    const int lane = tid & 63;
    const int wv = tid >> 6;
    const int N = BB * TT;       // 65536
    const int CHUNK = N / 256;   // 256 ints = 64 int4
    const int4* v4 = (const int4*)ids;
    const int b4 = tid * (CHUNK / 4);

    int cnt = 0;
#pragma unroll 4
    for (int i = 0; i < CHUNK / 4; ++i) {
        int4 v = v4[b4 + i];
        cnt += (v.x == 0 || (unsigned)v.x >= VOCABN);
        cnt += (v.y == 0 || (unsigned)v.y >= VOCABN);
        cnt += (v.z == 0 || (unsigned)v.z >= VOCABN);
        cnt += (v.w == 0 || (unsigned)v.w >= VOCABN);
    }
    int scan = cnt;
#pragma unroll
    for (int off = 1; off < 64; off <<= 1) {
        int n = __shfl_up(scan, off);
        if (lane >= off) scan += n;
    }
    __shared__ int wtot[4], wexcl[4];
    __shared__ int total;
    if (lane == 63) wtot[wv] = scan;
    __syncthreads();
    if (tid == 0) {
        int run = 0;
#pragma unroll
        for (int i = 0; i < 4; ++i) { wexcl[i] = run; run += wtot[i]; }
        total = run;
    }
    __syncthreads();
    int off = wexcl[wv] + scan - cnt;

    const int base = tid * CHUNK;
#pragma unroll 4
    for (int i = 0; i < CHUNK / 4; ++i) {
        int4 v = v4[b4 + i];
        if (v.x == 0 || (unsigned)v.x >= VOCABN) list[off++] = base + 4 * i;
        if (v.y == 0 || (unsigned)v.y >= VOCABN) list[off++] = base + 4 * i + 1;
        if (v.z == 0 || (unsigned)v.z >= VOCABN) list[off++] = base + 4 * i + 2;
        if (v.w == 0 || (unsigned)v.w >= VOCABN) list[off++] = base + 4 * i + 3;
    }
    __syncthreads();
    if (tid < QLEN) {
        const int K = total;
        const int Kc = K < QLEN ? K : QLEN;
        float ii = -1.0f, jj = -1.0f;
        if (tid >= QLEN - Kc) {
            int pos = list[K - QLEN + tid];
            ii = (float)(pos >> 10);
            jj = (float)(pos & (TT - 1));
        }
        outq[2 * tid] = ii;
        outq[2 * tid + 1] = jj;
    }
}

// ---------------------------------------------------------------------------
extern "C" void kernel_launch(void* const* d_in, const int* in_sizes, int n_in,
                              void* d_out, int out_size, void* d_ws, size_t ws_size,
                              hipStream_t stream) {
    const int* ids   = (const int*)d_in[0];
    const float* emb = (const float*)d_in[1];
    const float* kl  = (const float*)d_in[2];
    const float* rk  = (const float*)d_in[3];
    const float* bl  = (const float*)d_in[4];
    const float* W1  = (const float*)d_in[5];
    const float* b1  = (const float*)d_in[6];
    const float* W2  = (const float*)d_in[7];
    const float* b2  = (const float*)d_in[8];
    float* out = (float*)d_out;

    char* ws = (char*)d_ws;
    const size_t XG_ELEMS = (size_t)BB * TT * GG;   // 8,388,608
    const size_t H_ELEMS  = (size_t)BB * TT * DD;   // 2,097,152
    float* xg   = (float*)ws;
    float* h    = (float*)(ws + XG_ELEMS * 4);
    float* ctx  = (float*)(ws + (XG_ELEMS + H_ELEMS) * 4);
    int* list   = (int*)  (ws + (XG_ELEMS + 2 * H_ELEMS) * 4);

    k_xg<<<512, 128, 0, stream>>>(ids, emb, kl, bl, xg);
    k_lstm_scan<<<BB / BPW, 64, 0, stream>>>(xg, rk, h);
    k_attn<<<BB * 16, 256, 0, stream>>>(h, ctx);
    k_ymlp<<<BB, 256, 0, stream>>>(ctx, h, W1, b1, W2, b2, out);
    k_queue<<<1, 256, 0, stream>>>(ids, list, out + BB * DD);
}

// Round 7
// 585.348 us; speedup vs baseline: 2.2870x; 2.2870x over previous
//
#include <hip/hip_runtime.h>
#include <math.h>

#define BB 64
#define TT 1024
#define DD 32
#define GG 128   // 4*D
#define VOCABN 10000
#define QLEN 100

typedef float f32x2 __attribute__((ext_vector_type(2)));

__device__ __forceinline__ float fsig(float x) {
    return __builtin_amdgcn_rcpf(1.0f + __expf(-x));
}
__device__ __forceinline__ float readlane_f(float v, int l) {
    return __int_as_float(__builtin_amdgcn_readlane(__float_as_int(v), l));
}

// ---------------------------------------------------------------------------
// Kernel 1: xg[b,t,j] = b_lstm[j] + sum_d emb[id[b,t],d] * k_lstm[d,j]
// 4 tokens per barrier pair.
// ---------------------------------------------------------------------------
__global__ __launch_bounds__(128) void k_xg(const int* __restrict__ ids,
                                            const float* __restrict__ emb,
                                            const float* __restrict__ klstm,
                                            const float* __restrict__ bias,
                                            float* __restrict__ xg) {
    const int j = threadIdx.x;  // 0..127
    float kc[DD];
#pragma unroll
    for (int d = 0; d < DD; ++d) kc[d] = klstm[d * GG + j];
    const float bj = bias[j];
    __shared__ float e4[4][DD];
    const int PPB = (BB * TT) / gridDim.x;  // 128 tokens per block
    const int p0 = blockIdx.x * PPB;
    for (int p = p0; p < p0 + PPB; p += 4) {
        {
            int tok = p + (j >> 5);
            int id = ids[tok];
            if ((unsigned)id >= VOCABN) id = 0;
            e4[j >> 5][j & 31] = emb[id * DD + (j & 31)];
        }
        __syncthreads();
#pragma unroll
        for (int i = 0; i < 4; ++i) {
            float z = bj;
#pragma unroll
            for (int d = 0; d < DD; ++d) z += e4[i][d] * kc[d];
            xg[(size_t)(p + i) * GG + j] = z;
        }
        __syncthreads();
    }
}

// ---------------------------------------------------------------------------
// Kernel 2: LSTM scan — EXACT R3 version (measured 311 µs, VGPR 132).
// One wave per batch, 2 gate columns per lane; h broadcast via readlane.
// R5 lesson (recorded): multi-batch-per-wave trades 4x CU parallelism for
// only 1.2x ILP — never again. This shape is the structural floor (~730
// cyc/step: ~260 issue on a single resident wave + serial trans/shfl chain).
// ---------------------------------------------------------------------------
#define UU 8
__global__
__attribute__((amdgpu_flat_work_group_size(64, 64)))
__attribute__((amdgpu_waves_per_eu(1, 1)))
void k_lstm_scan(const float* __restrict__ xg,
                 const float* __restrict__ rk,
                 float* __restrict__ hout) {
    const int b = blockIdx.x;
    const int l = threadIdx.x;       // 0..63
    const int d = l & 31;
    const bool hi = l >= 32;
    const int ga = (hi ? 32 : 0) + d;   // i (lo) / f (hi)
    const int gb = (hi ? 96 : 64) + d;  // g (lo) / o (hi)
    float rka[DD], rkb[DD];
#pragma unroll
    for (int k = 0; k < DD; ++k) { rka[k] = rk[k * GG + ga]; rkb[k] = rk[k * GG + gb]; }
    const float* xgb = xg + (size_t)b * TT * GG;
    float* hb = hout + (size_t)b * TT * DD;

    float pa[UU], pb[UU];
#pragma unroll
    for (int u = 0; u < UU; ++u) { pa[u] = xgb[u * GG + ga]; pb[u] = xgb[u * GG + gb]; }

    float h = 0.0f, c = 0.0f;
    for (int t0 = 0; t0 < TT; t0 += UU) {
        float na[UU], nb[UU];
        const int tn0 = (t0 + UU < TT) ? (t0 + UU) : t0;
#pragma unroll
        for (int u = 0; u < UU; ++u) {
            na[u] = xgb[(tn0 + u) * GG + ga];
            nb[u] = xgb[(tn0 + u) * GG + gb];
        }
#pragma unroll
        for (int u = 0; u < UU; ++u) {
            float za0 = pa[u], zb0 = pb[u];
            float za1 = 0.f, za2 = 0.f, za3 = 0.f;
            float zb1 = 0.f, zb2 = 0.f, zb3 = 0.f;
#pragma unroll
            for (int k = 0; k < DD; k += 4) {
                float h0 = readlane_f(h, k);
                float h1 = readlane_f(h, k + 1);
                float h2 = readlane_f(h, k + 2);
                float h3 = readlane_f(h, k + 3);
                za0 = fmaf(h0, rka[k], za0);     zb0 = fmaf(h0, rkb[k], zb0);
                za1 = fmaf(h1, rka[k + 1], za1); zb1 = fmaf(h1, rkb[k + 1], zb1);
                za2 = fmaf(h2, rka[k + 2], za2); zb2 = fmaf(h2, rkb[k + 2], zb2);
                za3 = fmaf(h3, rka[k + 3], za3); zb3 = fmaf(h3, rkb[k + 3], zb3);
            }
            float za = (za0 + za1) + (za2 + za3);
            float zb = (zb0 + zb1) + (zb2 + zb3);
            float a = fsig(za);                       // sig(i) lo / sig(f) hi
            float zbm = hi ? zb : 2.0f * zb;
            float s2 = fsig(zbm);
            float bv = hi ? s2 : 2.0f * s2 - 1.0f;    // sig(o) hi / tanh(g) lo
            float fg = __shfl_xor(a, 32);             // lo lanes get sig(f)
            float og = __shfl_xor(bv, 32);            // lo lanes get sig(o)
            c = fmaf(fg, c, a * bv);                  // sig(f)*c + sig(i)*tanh(g)
            float tc = 2.0f * fsig(2.0f * c) - 1.0f;  // tanh(c)
            h = og * tc;
            if (!hi) hb[(t0 + u) * DD + d] = h;
        }
#pragma unroll
        for (int u = 0; u < UU; ++u) { pa[u] = na[u]; pb[u] = nb[u]; }
    }
}

// ---------------------------------------------------------------------------
// Kernel 3: attention — R1 structure (proven correct/fast), inner loop
// rewritten on f32x2 ext-vectors + __builtin_elementwise_fma, targeting
// v_pk_fma_f32 (2 MACs/inst) to halve the per-key VALU issue count.
// Split-K flash, no max-subtraction (|score|<=32, exp can't overflow).
// ---------------------------------------------------------------------------
__global__ __launch_bounds__(256, 4) void k_attn(const float* __restrict__ h,
                                                 float* __restrict__ ctx) {
    __shared__ float smem[4 * 64 * DD];  // 32 KB: 4 wave-private key tiles
    const int tid = threadIdx.x;
    const int w = tid >> 6;     // split / wave id
    const int lane = tid & 63;  // q row within tile
    const int b = blockIdx.x >> 4;
    const int qt = blockIdx.x & 15;
    const float* hb = h + (size_t)b * TT * DD;
    const int q = qt * 64 + lane;

    f32x2 qq[16], aa[16];
    {
        const float4* qsrc = (const float4*)(hb + (size_t)q * DD);
#pragma unroll
        for (int n = 0; n < 8; ++n) {
            float4 v = qsrc[n];
            qq[2 * n]     = (f32x2){v.x, v.y};
            qq[2 * n + 1] = (f32x2){v.z, v.w};
        }
    }
#pragma unroll
    for (int n = 0; n < 16; ++n) aa[n] = (f32x2){0.0f, 0.0f};
    float l = 0.0f;

    float* myk = smem + w * (64 * DD);
#pragma unroll 1
    for (int tile = 0; tile < 4; ++tile) {
        const float4* ksrc = (const float4*)(hb + (size_t)(w * 256 + tile * 64) * DD);
        float4* kd = (float4*)myk;
#pragma unroll
        for (int n = 0; n < 8; ++n) kd[lane + n * 64] = ksrc[lane + n * 64];
        // wave-private region: same-wave ds write->read ordering, no barrier
        for (int s = 0; s < 64; ++s) {
            const float4* kr = (const float4*)(myk + s * DD);
            f32x2 kk[16];
#pragma unroll
            for (int n = 0; n < 8; ++n) {
                float4 v = kr[n];
                kk[2 * n]     = (f32x2){v.x, v.y};
                kk[2 * n + 1] = (f32x2){v.z, v.w};
            }
            f32x2 d0 = {0.f, 0.f}, d1 = {0.f, 0.f}, d2 = {0.f, 0.f}, d3 = {0.f, 0.f};
#pragma unroll
            for (int n = 0; n < 16; n += 4) {
                d0 = __builtin_elementwise_fma(kk[n],     qq[n],     d0);
                d1 = __builtin_elementwise_fma(kk[n + 1], qq[n + 1], d1);
                d2 = __builtin_elementwise_fma(kk[n + 2], qq[n + 2], d2);
                d3 = __builtin_elementwise_fma(kk[n + 3], qq[n + 3], d3);
            }
            f32x2 ds = (d0 + d1) + (d2 + d3);
            float sc = ds.x + ds.y;
            float e = __expf(sc);
            l += e;
            f32x2 e2 = {e, e};
#pragma unroll
            for (int n = 0; n < 16; ++n)
                aa[n] = __builtin_elementwise_fma(e2, kk[n], aa[n]);
        }
    }

    // merge splits: sequential adds into macc[64][33] (reuses tile LDS)
    const float* av = (const float*)aa;
    float* macc = smem;
    for (int ww = 0; ww < 4; ++ww) {
        __syncthreads();
        if (w == ww) {
            if (ww == 0) {
#pragma unroll
                for (int n = 0; n < DD; ++n) macc[lane * 33 + n] = av[n];
                macc[lane * 33 + 32] = l;
            } else {
#pragma unroll
                for (int n = 0; n < DD; ++n) macc[lane * 33 + n] += av[n];
                macc[lane * 33 + 32] += l;
            }
        }
    }
    __syncthreads();
    {
        const int r = tid >> 2;          // 0..63
        const int c0 = (tid & 3) * 8;    // 0,8,16,24
        float linv = __builtin_amdgcn_rcpf(macc[r * 33 + 32]);
        float o[8];
#pragma unroll
        for (int jj = 0; jj < 8; ++jj) o[jj] = macc[r * 33 + c0 + jj] * linv;
        float* crow = ctx + (size_t)b * TT * DD + (size_t)qt * 64 * DD;
        ((float4*)(crow + tid * 8))[0] = make_float4(o[0], o[1], o[2], o[3]);
        ((float4*)(crow + tid * 8))[1] = make_float4(o[4], o[5], o[6], o[7]);
    }
}

// ---------------------------------------------------------------------------
// Kernel 4: y[b,d,e] = sum_t ctx[b,t,d]*h[b,t,e];  yr = relu(y@W1+b1);
// out[b,d] = sigmoid(yr@W2+b2).  One block per batch, 256 threads.
// ---------------------------------------------------------------------------
__global__ __launch_bounds__(256) void k_ymlp(const float* __restrict__ ctx,
                                              const float* __restrict__ h,
                                              const float* __restrict__ W1,
                                              const float* __restrict__ b1,
                                              const float* __restrict__ W2,
                                              const float* __restrict__ b2,
                                              float* __restrict__ out) {
    const int b = blockIdx.x;
    const int tid = threadIdx.x;
    __shared__ __align__(16) float cs[128 * DD];
    __shared__ __align__(16) float hs[128 * DD];
    const float* cb = ctx + (size_t)b * TT * DD;
    const float* hb = h + (size_t)b * TT * DD;
    const int e = tid & 31;
    const int d0 = tid >> 5;
    float acc[4] = {0.f, 0.f, 0.f, 0.f};
    for (int kt = 0; kt < 8; ++kt) {
        const float4* s1 = (const float4*)(cb + (size_t)kt * 128 * DD);
        const float4* s2 = (const float4*)(hb + (size_t)kt * 128 * DD);
        float4* t1 = (float4*)cs;
        float4* t2 = (float4*)hs;
#pragma unroll
        for (int n = 0; n < 4; ++n) {
            t1[tid + n * 256] = s1[tid + n * 256];
            t2[tid + n * 256] = s2[tid + n * 256];
        }
        __syncthreads();
        for (int s = 0; s < 128; ++s) {
            float hv = hs[s * DD + e];
#pragma unroll
            for (int r = 0; r < 4; ++r) acc[r] += cs[s * DD + d0 + 8 * r] * hv;
        }
        __syncthreads();
    }
    __shared__ float ys[DD][DD];
#pragma unroll
    for (int r = 0; r < 4; ++r) ys[d0 + 8 * r][e] = acc[r];
    __syncthreads();
    __shared__ float yr[DD][33];
#pragma unroll
    for (int r = 0; r < 4; ++r) {
        float v = b1[e];
#pragma unroll
        for (int ee = 0; ee < DD; ++ee) v += ys[d0 + 8 * r][ee] * W1[ee * DD + e];
        yr[d0 + 8 * r][e] = fmaxf(v, 0.0f);
    }
    __syncthreads();
    if (tid < DD) {
        float v = b2[0];
#pragma unroll
        for (int ee = 0; ee < DD; ++ee) v += yr[tid][ee] * W2[ee];
        out[b * DD + tid] = 1.0f / (1.0f + expf(-v));
    }
}

// ---------------------------------------------------------------------------
// Kernel 5: zero-index queue. int4 loads + wave shfl-scan.
// ---------------------------------------------------------------------------
__global__ __launch_bounds__(256) void k_queue(const int* __restrict__ ids,
                                               int* __restrict__ list,
                                               float* __restrict__ outq) {
    const int tid = threadIdx.x;
    const int lane = tid & 63;
    const int wv = tid >> 6;
    const int N = BB * TT;       // 65536
    const int CHUNK = N / 256;   // 256 ints = 64 int4
    const int4* v4 = (const int4*)ids;
    const int b4 = tid * (CHUNK / 4);

    int cnt = 0;
#pragma unroll 4
    for (int i = 0; i < CHUNK / 4; ++i) {
        int4 v = v4[b4 + i];
        cnt += (v.x == 0 || (unsigned)v.x >= VOCABN);
        cnt += (v.y == 0 || (unsigned)v.y >= VOCABN);
        cnt += (v.z == 0 || (unsigned)v.z >= VOCABN);
        cnt += (v.w == 0 || (unsigned)v.w >= VOCABN);
    }
    int scan = cnt;
#pragma unroll
    for (int off = 1; off < 64; off <<= 1) {
        int n = __shfl_up(scan, off);
        if (lane >= off) scan += n;
    }
    __shared__ int wtot[4], wexcl[4];
    __shared__ int total;
    if (lane == 63) wtot[wv] = scan;
    __syncthreads();
    if (tid == 0) {
        int run = 0;
#pragma unroll
        for (int i = 0; i < 4; ++i) { wexcl[i] = run; run += wtot[i]; }
        total = run;
    }
    __syncthreads();
    int off = wexcl[wv] + scan - cnt;

    const int base = tid * CHUNK;
#pragma unroll 4
    for (int i = 0; i < CHUNK / 4; ++i) {
        int4 v = v4[b4 + i];
        if (v.x == 0 || (unsigned)v.x >= VOCABN) list[off++] = base + 4 * i;
        if (v.y == 0 || (unsigned)v.y >= VOCABN) list[off++] = base + 4 * i + 1;
        if (v.z == 0 || (unsigned)v.z >= VOCABN) list[off++] = base + 4 * i + 2;
        if (v.w == 0 || (unsigned)v.w >= VOCABN) list[off++] = base + 4 * i + 3;
    }
    __syncthreads();
    if (tid < QLEN) {
        const int K = total;
        const int Kc = K < QLEN ? K : QLEN;
        float ii = -1.0f, jj = -1.0f;
        if (tid >= QLEN - Kc) {
            int pos = list[K - QLEN + tid];
            ii = (float)(pos >> 10);
            jj = (float)(pos & (TT - 1));
        }
        outq[2 * tid] = ii;
        outq[2 * tid + 1] = jj;
    }
}

// ---------------------------------------------------------------------------
extern "C" void kernel_launch(void* const* d_in, const int* in_sizes, int n_in,
                              void* d_out, int out_size, void* d_ws, size_t ws_size,
                              hipStream_t stream) {
    const int* ids   = (const int*)d_in[0];
    const float* emb = (const float*)d_in[1];
    const float* kl  = (const float*)d_in[2];
    const float* rk  = (const float*)d_in[3];
    const float* bl  = (const float*)d_in[4];
    const float* W1  = (const float*)d_in[5];
    const float* b1  = (const float*)d_in[6];
    const float* W2  = (const float*)d_in[7];
    const float* b2  = (const float*)d_in[8];
    float* out = (float*)d_out;

    char* ws = (char*)d_ws;
    const size_t XG_ELEMS = (size_t)BB * TT * GG;   // 8,388,608
    const size_t H_ELEMS  = (size_t)BB * TT * DD;   // 2,097,152
    float* xg   = (float*)ws;
    float* h    = (float*)(ws + XG_ELEMS * 4);
    float* ctx  = (float*)(ws + (XG_ELEMS + H_ELEMS) * 4);
    int* list   = (int*)  (ws + (XG_ELEMS + 2 * H_ELEMS) * 4);

    k_xg<<<512, 128, 0, stream>>>(ids, emb, kl, bl, xg);
    k_lstm_scan<<<BB, 64, 0, stream>>>(xg, rk, h);
    k_attn<<<BB * 16, 256, 0, stream>>>(h, ctx);
    k_ymlp<<<BB, 256, 0, stream>>>(ctx, h, W1, b1, W2, b2, out);
    k_queue<<<1, 256, 0, stream>>>(ids, list, out + BB * DD);
}